// Round 16
// baseline (276.252 us; speedup 1.0000x reference)
//
#include <hip/hip_runtime.h>
#include <hip/hip_cooperative_groups.h>
#include <hip/hip_bf16.h>
#include <math.h>

namespace cg = cooperative_groups;

typedef __bf16 bf16;
typedef __attribute__((ext_vector_type(8))) __bf16 bf16x8;
typedef __attribute__((ext_vector_type(4))) __bf16 bf16x4;
typedef __attribute__((ext_vector_type(4))) float f32x4;

#define B_  2
#define T_  2048
#define C_  1024
#define H_  16
#define HD_ 64
#define WIN_ 256

#define GLOAD16(g, l)                                                        \
  __builtin_amdgcn_global_load_lds(                                          \
      (const __attribute__((address_space(1))) void*)(g),                    \
      (__attribute__((address_space(3))) void*)(l), 16, 0, 0)

__device__ inline void bar() {
  asm volatile("" ::: "memory");
  __builtin_amdgcn_s_barrier();
  asm volatile("" ::: "memory");
}

// ================= phase bodies (shared by fused + standalone) =================

// ---- prologue: 512 blocks x 512 thr. cvt x (4 float4/thr) + 8 transpose tiles/blk
__device__ __forceinline__ void prologue_phase(const float* __restrict__ x,
                                               bf16* __restrict__ xb,
                                               const float* __restrict__ Wqkv,
                                               bf16* __restrict__ wqkvT,
                                               const float* __restrict__ Wproj,
                                               bf16* __restrict__ wprojT,
                                               float* tf, int bid) {
  const int tid = threadIdx.x;
  #pragma unroll
  for (int i = 0; i < 4; ++i) {
    const int idx = (bid * 512 + tid) + i * 262144;
    const float4 v = ((const float4*)x)[idx];
    bf16x4 o;
    o[0] = (bf16)v.x; o[1] = (bf16)v.y; o[2] = (bf16)v.z; o[3] = (bf16)v.w;
    ((bf16x4*)xb)[idx] = o;
  }
  const int half = tid >> 8;
  const int st = tid & 255;
  const int tx = st & 31, ty = st >> 5;
  float* tt = tf + half * (32 * 33);
  for (int j = 0; j < 4; ++j) {
    const int tile = bid * 8 + j * 2 + half;   // 0..4095
    const float* W; bf16* WT; int N, tb;
    if (tile < 3072) { tb = tile;        W = Wqkv;  WT = wqkvT;  N = 3 * C_; }
    else             { tb = tile - 3072; W = Wproj; WT = wprojT; N = C_;     }
    const int xt = N / 32;
    const int n0 = (tb % xt) * 32, k0 = (tb / xt) * 32;
    #pragma unroll
    for (int i = 0; i < 32; i += 8)
      tt[(ty + i) * 33 + tx] = W[(size_t)(k0 + ty + i) * N + (n0 + tx)];
    __syncthreads();
    #pragma unroll
    for (int i = 0; i < 32; i += 8)
      WT[(size_t)(n0 + ty + i) * C_ + (k0 + tx)] = (bf16)tt[tx * 33 + (ty + i)];
    __syncthreads();
  }
}

// ---- double-buffered GEMM (R9/R13 winning structure), pool-based LDS
template <int TM, int TN, int WM, int WN, int MODE>
__device__ __forceinline__ void gemm_phase(const bf16* __restrict__ A,
                                           const bf16* __restrict__ Bt,
                                           const float* __restrict__ bias,
                                           void* __restrict__ out0,
                                           void* __restrict__ out1,
                                           int M, int N, int K,
                                           bf16* pool, int bx, int by) {
  constexpr int NW    = WM * WN;
  constexpr int WROWS = TM / WM;
  constexpr int WCOLS = TN / WN;
  constexpr int FM    = WROWS / 16;
  constexpr int FN    = WCOLS / 16;
  constexpr int NCH   = (TM + TN) / 8;
  constexpr int CPW   = NCH / NW;

  bf16* As = pool;                  // [2][TM*64]
  bf16* Bs = pool + 2 * TM * 64;    // [2][TN*64]

  const int bm = bx * TM;
  const int bn = by * TN;
  const int tid  = threadIdx.x;
  const int wid  = tid >> 6;
  const int lane = tid & 63;
  const int wr = wid / WN;
  const int wc = wid % WN;
  const int lr = lane & 15;
  const int g  = lane >> 4;

  f32x4 acc[FM][FN] = {};

  const int sr = lane >> 3;
  const int sc = ((lane & 7) ^ sr) << 3;

  #define STGF(p_, u_)                                                       \
    do {                                                                     \
      _Pragma("unroll")                                                      \
      for (int i = 0; i < CPW; ++i) {                                        \
        const int c = wid * CPW + i;                                         \
        if (c < TM / 8) {                                                    \
          GLOAD16(A + (size_t)(bm + c * 8 + sr) * K + (u_) * 64 + sc,        \
                  As + (p_) * TM * 64 + c * 8 * 64);                         \
        } else {                                                             \
          GLOAD16(Bt + (size_t)(bn + (c - TM / 8) * 8 + sr) * K + (u_) * 64 + sc, \
                  Bs + (p_) * TN * 64 + (c - TM / 8) * 8 * 64);              \
        }                                                                    \
      }                                                                      \
    } while (0)

  const int NT = K >> 6;
  const int kc0 = ((0 + g) ^ (lr & 7)) << 3;
  const int kc1 = ((4 + g) ^ (lr & 7)) << 3;

  STGF(0, 0);
  asm volatile("s_waitcnt vmcnt(0)" ::: "memory");
  __builtin_amdgcn_s_barrier();
  asm volatile("" ::: "memory");

  for (int u = 0; u < NT; ++u) {
    const int p = u & 1;
    if (u + 1 < NT) {
      STGF(p ^ 1, u + 1);
      asm volatile("s_waitcnt vmcnt(%0)" :: "i"(CPW) : "memory");
    } else {
      asm volatile("s_waitcnt vmcnt(0)" ::: "memory");
    }
    bar();

    const bf16* Ar = As + p * TM * 64 + (wr * WROWS + lr) * 64;
    const bf16* Br = Bs + p * TN * 64 + (wc * WCOLS + lr) * 64;
    #pragma unroll
    for (int s = 0; s < 2; ++s) {
      const int kc = s ? kc1 : kc0;
      bf16x8 av[FM], bvv[FN];
      #pragma unroll
      for (int m = 0; m < FM; ++m)
        av[m] = *(const bf16x8*)(Ar + m * 16 * 64 + kc);
      #pragma unroll
      for (int n = 0; n < FN; ++n)
        bvv[n] = *(const bf16x8*)(Br + n * 16 * 64 + kc);
      __builtin_amdgcn_s_setprio(1);
      #pragma unroll
      for (int m = 0; m < FM; ++m)
        #pragma unroll
        for (int n = 0; n < FN; ++n)
          acc[m][n] = __builtin_amdgcn_mfma_f32_16x16x32_bf16(av[m], bvv[n], acc[m][n], 0, 0, 0);
      __builtin_amdgcn_s_setprio(0);
    }
    bar();
  }
  #undef STGF

  const int orow = g * 4;
  #pragma unroll
  for (int n = 0; n < FN; ++n) {
    const int nbase = bn + wc * WCOLS + n * 16;
    const int gn = nbase + lr;
    const float bv_ = bias[gn];
    #pragma unroll
    for (int m = 0; m < FM; ++m) {
      const int gm0 = bm + wr * WROWS + m * 16 + orow;
      if (MODE == 0) {
        #pragma unroll
        for (int r = 0; r < 4; ++r)
          ((float*)out0)[(size_t)(gm0 + r) * N + gn] = acc[m][n][r] + bv_;
      } else {
        if (nbase < 2 * C_) {
          #pragma unroll
          for (int r = 0; r < 4; ++r)
            ((bf16*)out0)[(size_t)(gm0 + r) * (2 * C_) + gn] = (bf16)(acc[m][n][r] + bv_);
        } else {
          const int vcol = gn - 2 * C_;
          const int h = vcol >> 6, d = vcol & 63;
          const int b = gm0 >> 11, tok = gm0 & (T_ - 1);
          bf16x4 o;
          #pragma unroll
          for (int r = 0; r < 4; ++r) o[r] = (bf16)(acc[m][n][r] + bv_);
          *(bf16x4*)&((bf16*)out1)[(((size_t)b * H_ + h) * HD_ + d) * T_ + tok] = o;
        }
      }
    }
  }
}

// ---- attn (R13 winning structure), pool-based LDS
__device__ __forceinline__ void attn_phase(const bf16* __restrict__ qk,
                                           const bf16* __restrict__ vt,
                                           bf16* __restrict__ y,
                                           bf16* pool, int bx, int h, int b) {
  bf16* Ks = pool;             // [2][4096]
  bf16* Vs = pool + 8192;      // [2][4096]
  bf16* Ps = pool + 16384;     // [8][16][72]

  const int q0 = bx * 128;
  const int tid  = threadIdx.x;
  const int wid  = tid >> 6;
  const int lane = tid & 63;
  const int lr = lane & 15;
  const int g  = lane >> 4;

  const int qrow = q0 + wid * 16 + lr;
  const bf16* qptr = qk + ((size_t)(b * T_ + qrow)) * (2 * C_) + h * HD_;
  bf16x8 qf0 = *(const bf16x8*)(qptr + g * 8);
  bf16x8 qf1 = *(const bf16x8*)(qptr + 32 + g * 8);

  float m = -1e30f, l = 0.f;
  f32x4 yacc[4] = {};

  const int kt_lo = (bx * 2 >= 4) ? bx * 2 - 4 : 0;
  const int kt_hi = bx * 2 + 1;

  const int sr = lane >> 3;
  const int sc = ((lane & 7) ^ sr) << 3;
  const int kc0 = ((0 + g) ^ (lr & 7)) << 3;
  const int kc1 = ((4 + g) ^ (lr & 7)) << 3;

  #define STAGEKV(p_, kt_)                                                     \
    do {                                                                       \
      _Pragma("unroll")                                                        \
      for (int i = 0; i < 2; ++i) {                                            \
        const int c = wid * 2 + i;                                             \
        if (c < 8)                                                             \
          GLOAD16(qk + ((size_t)(b * T_) + (kt_) * 64 + c * 8 + sr) * (2 * C_) \
                       + C_ + h * HD_ + sc,                                    \
                  Ks + (p_) * 4096 + c * 8 * 64);                              \
        else                                                                   \
          GLOAD16(vt + (((size_t)b * H_ + h) * HD_ + (c - 8) * 8 + sr) * T_    \
                       + (kt_) * 64 + sc,                                      \
                  Vs + (p_) * 4096 + (c - 8) * 8 * 64);                        \
      }                                                                        \
    } while (0)

  STAGEKV(0, kt_lo);
  asm volatile("s_waitcnt vmcnt(0)" ::: "memory");
  bar();

  for (int kt = kt_lo; kt <= kt_hi; ++kt) {
    const int idx = kt - kt_lo;
    const int p   = idx & 1;
    if (kt + 1 <= kt_hi) {
      STAGEKV(p ^ 1, kt + 1);
      asm volatile("s_waitcnt vmcnt(2)" ::: "memory");
    } else {
      asm volatile("s_waitcnt vmcnt(0)" ::: "memory");
    }
    bar();

    const int wq = q0 + wid * 16;
    if (kt * 64 <= wq + 15 && kt * 64 + 63 >= wq - WIN_) {
      f32x4 sacc[4] = {};
      __builtin_amdgcn_s_setprio(1);
      #pragma unroll
      for (int t = 0; t < 4; ++t) {
        sacc[t] = __builtin_amdgcn_mfma_f32_16x16x32_bf16(
            *(const bf16x8*)(Ks + p * 4096 + (t * 16 + lr) * 64 + kc0), qf0, sacc[t], 0, 0, 0);
        sacc[t] = __builtin_amdgcn_mfma_f32_16x16x32_bf16(
            *(const bf16x8*)(Ks + p * 4096 + (t * 16 + lr) * 64 + kc1), qf1, sacc[t], 0, 0, 0);
      }
      __builtin_amdgcn_s_setprio(0);

      float pv[4][4];
      float rmax = -1e30f;
      #pragma unroll
      for (int t = 0; t < 4; ++t)
        #pragma unroll
        for (int r = 0; r < 4; ++r) {
          const int key = kt * 64 + t * 16 + g * 4 + r;
          const bool valid = (key <= qrow) && (qrow - key <= WIN_);
          const float sv = valid ? sacc[t][r] * 0.125f : -__builtin_inff();
          pv[t][r] = sv;
          rmax = fmaxf(rmax, sv);
        }
      rmax = fmaxf(rmax, __shfl_xor(rmax, 16));
      rmax = fmaxf(rmax, __shfl_xor(rmax, 32));

      const float mnew = fmaxf(m, rmax);
      const float alpha = __expf(m - mnew);
      m = mnew;
      float lsum = 0.f;
      #pragma unroll
      for (int t = 0; t < 4; ++t)
        #pragma unroll
        for (int r = 0; r < 4; ++r) {
          const float e = __expf(pv[t][r] - mnew);
          pv[t][r] = e;
          lsum += e;
        }
      lsum += __shfl_xor(lsum, 16);
      lsum += __shfl_xor(lsum, 32);
      l = l * alpha + lsum;

      #pragma unroll
      for (int t = 0; t < 4; ++t) {
        bf16x4 pk;
        #pragma unroll
        for (int r = 0; r < 4; ++r) pk[r] = (bf16)pv[t][r];
        *(bf16x4*)(Ps + (wid * 16 + lr) * 72 + t * 16 + g * 4) = pk;
      }

      float al[4];
      #pragma unroll
      for (int r = 0; r < 4; ++r) al[r] = __shfl(alpha, g * 4 + r);
      #pragma unroll
      for (int t = 0; t < 4; ++t)
        #pragma unroll
        for (int r = 0; r < 4; ++r) yacc[t][r] *= al[r];

      bf16x8 pf0 = *(const bf16x8*)(Ps + (wid * 16 + lr) * 72 + g * 8);
      bf16x8 pf1 = *(const bf16x8*)(Ps + (wid * 16 + lr) * 72 + 32 + g * 8);
      __builtin_amdgcn_s_setprio(1);
      #pragma unroll
      for (int t = 0; t < 4; ++t) {
        yacc[t] = __builtin_amdgcn_mfma_f32_16x16x32_bf16(
            pf0, *(const bf16x8*)(Vs + p * 4096 + (t * 16 + lr) * 64 + kc0), yacc[t], 0, 0, 0);
        yacc[t] = __builtin_amdgcn_mfma_f32_16x16x32_bf16(
            pf1, *(const bf16x8*)(Vs + p * 4096 + (t * 16 + lr) * 64 + kc1), yacc[t], 0, 0, 0);
      }
      __builtin_amdgcn_s_setprio(0);
    }
    bar();
  }
  #undef STAGEKV

  float li[4];
  #pragma unroll
  for (int r = 0; r < 4; ++r) li[r] = 1.f / __shfl(l, g * 4 + r);
  #pragma unroll
  for (int t = 0; t < 4; ++t)
    #pragma unroll
    for (int r = 0; r < 4; ++r) {
      const int tok = q0 + wid * 16 + g * 4 + r;
      y[((size_t)(b * T_ + tok)) * C_ + h * HD_ + t * 16 + lr] = (bf16)(yacc[t][r] * li[r]);
    }
}

// ================= fused cooperative kernel =================
// 512 blocks x 512 thr, 80KB LDS -> exactly 2 blocks/CU = 512 co-resident.

__global__ __launch_bounds__(512, 4) void fused_k(
    const float* __restrict__ x, bf16* __restrict__ xb,
    const float* __restrict__ Wqkv, bf16* __restrict__ wqkvT,
    const float* __restrict__ Wproj, bf16* __restrict__ wprojT,
    const float* __restrict__ bqkv, const float* __restrict__ bproj,
    bf16* __restrict__ qkb, bf16* __restrict__ vtb,
    bf16* __restrict__ yb, float* __restrict__ out) {
  __shared__ __align__(16) bf16 pool[40960];   // 80 KB, unioned across phases
  cg::grid_group grid = cg::this_grid();
  const int bid = blockIdx.x;

  prologue_phase(x, xb, Wqkv, wqkvT, Wproj, wprojT, (float*)pool, bid);
  grid.sync();
  gemm_phase<128, 192, 2, 4, 2>(xb, wqkvT, bqkv, qkb, vtb,
                                B_ * T_, 3 * C_, C_, pool, bid & 31, bid >> 5);
  grid.sync();
  attn_phase(qkb, vtb, yb, pool, bid & 15, (bid >> 4) & 15, bid >> 8);
  grid.sync();
  gemm_phase<64, 128, 2, 4, 0>(yb, wprojT, bproj, out, nullptr,
                               B_ * T_, C_, C_, pool, bid & 63, bid >> 6);
}

// ================= standalone fallback kernels (deterministic path) =================

__global__ __launch_bounds__(512) void prologue_k(const float* x, bf16* xb,
    const float* Wqkv, bf16* wqkvT, const float* Wproj, bf16* wprojT) {
  __shared__ __align__(16) float tf[2 * 32 * 33];
  prologue_phase(x, xb, Wqkv, wqkvT, Wproj, wprojT, tf, blockIdx.x);
}

__global__ __launch_bounds__(512, 4) void qkv_k(const bf16* A, const bf16* Bt,
    const float* bias, void* out0, void* out1) {
  __shared__ __align__(16) bf16 pool[40960];
  gemm_phase<128, 192, 2, 4, 2>(A, Bt, bias, out0, out1,
                                B_ * T_, 3 * C_, C_, pool, blockIdx.x, blockIdx.y);
}

__global__ __launch_bounds__(512) void attn_k(const bf16* qk, const bf16* vt, bf16* y) {
  __shared__ __align__(16) bf16 pool[25600];
  attn_phase(qk, vt, y, pool, blockIdx.x, blockIdx.y, blockIdx.z);
}

__global__ __launch_bounds__(512, 4) void proj_k(const bf16* A, const bf16* Bt,
    const float* bias, void* out0) {
  __shared__ __align__(16) bf16 pool[24576];
  gemm_phase<64, 128, 2, 4, 0>(A, Bt, bias, out0, nullptr,
                               B_ * T_, C_, C_, pool, blockIdx.x, blockIdx.y);
}

// ================= launch =================

extern "C" void kernel_launch(void* const* d_in, const int* in_sizes, int n_in,
                              void* d_out, int out_size, void* d_ws, size_t ws_size,
                              hipStream_t stream) {
  const float* x     = (const float*)d_in[0];
  const float* Wqkv  = (const float*)d_in[1];
  const float* bqkv  = (const float*)d_in[2];
  const float* Wproj = (const float*)d_in[3];
  const float* bproj = (const float*)d_in[4];
  float* out = (float*)d_out;

  const size_t SZ_QK  = (size_t)B_ * T_ * 2 * C_ * sizeof(bf16);
  const size_t SZ_VT  = (size_t)B_ * H_ * HD_ * T_ * sizeof(bf16);
  const size_t SZ_XB  = (size_t)B_ * T_ * C_ * sizeof(bf16);
  const size_t SZ_WQT = (size_t)3 * C_ * C_ * sizeof(bf16);
  const size_t SZ_WPT = (size_t)C_ * C_ * sizeof(bf16);
  const size_t NEED   = SZ_QK + SZ_VT + SZ_XB + SZ_WQT + SZ_WPT + SZ_XB;
  if (ws_size < NEED) return;

  char* ws = (char*)d_ws;
  bf16* qkb    = (bf16*)(ws);
  bf16* vtb    = (bf16*)(ws + SZ_QK);
  bf16* xb     = (bf16*)(ws + SZ_QK + SZ_VT);
  bf16* wqkvT  = (bf16*)(ws + SZ_QK + SZ_VT + SZ_XB);
  bf16* wprojT = (bf16*)(ws + SZ_QK + SZ_VT + SZ_XB + SZ_WQT);
  bf16* yb     = (bf16*)(ws + SZ_QK + SZ_VT + SZ_XB + SZ_WQT + SZ_WPT);

  void* args[] = {(void*)&x, (void*)&xb, (void*)&Wqkv, (void*)&wqkvT,
                  (void*)&Wproj, (void*)&wprojT, (void*)&bqkv, (void*)&bproj,
                  (void*)&qkb, (void*)&vtb, (void*)&yb, (void*)&out};
  hipError_t err = hipLaunchCooperativeKernel((void*)fused_k, dim3(512), dim3(512),
                                              args, 0, stream);
  if (err != hipSuccess) {
    // deterministic fallback: same phases as 4 kernels (≈ R13 structure)
    prologue_k<<<512, 512, 0, stream>>>(x, xb, Wqkv, wqkvT, Wproj, wprojT);
    qkv_k<<<dim3(32, 16), 512, 0, stream>>>(xb, wqkvT, bqkv, qkb, vtb);
    attn_k<<<dim3(16, 16, 2), 512, 0, stream>>>(qkb, vtb, yb);
    proj_k<<<dim3(64, 8), 512, 0, stream>>>(yb, wprojT, bproj, out);
  }
}

// Round 17
// 82.023 us; speedup vs baseline: 3.3680x; 3.3680x over previous
//
#include <hip/hip_runtime.h>
#include <hip/hip_bf16.h>
#include <math.h>

typedef __bf16 bf16;
typedef __attribute__((ext_vector_type(8))) __bf16 bf16x8;
typedef __attribute__((ext_vector_type(4))) __bf16 bf16x4;
typedef __attribute__((ext_vector_type(4))) float f32x4;

#define B_  2
#define T_  2048
#define C_  1024
#define H_  16
#define HD_ 64
#define WIN_ 256

// async global->LDS, 16B per lane, dest = wave-uniform base + lane*16
#define GLOAD16(g, l)                                                        \
  __builtin_amdgcn_global_load_lds(                                          \
      (const __attribute__((address_space(1))) void*)(g),                    \
      (__attribute__((address_space(3))) void*)(l), 16, 0, 0)

__device__ inline void bar() {
  asm volatile("" ::: "memory");
  __builtin_amdgcn_s_barrier();
  asm volatile("" ::: "memory");
}

// ---------------- merged prologue: cvt x + transpose both weights ----------------

__global__ __launch_bounds__(256) void prologue_k(const float* __restrict__ x,
                                                  bf16* __restrict__ xb,
                                                  const float* __restrict__ Wqkv,
                                                  bf16* __restrict__ wqkvT,
                                                  const float* __restrict__ Wproj,
                                                  bf16* __restrict__ wprojT) {
  __shared__ float t[32][33];
  const int blk = blockIdx.x;
  const int tid = threadIdx.x;

  if (blk < 4096) {
    const int idx = blk * 256 + tid;
    const float4 v = ((const float4*)x)[idx];
    bf16x4 o;
    o[0] = (bf16)v.x; o[1] = (bf16)v.y; o[2] = (bf16)v.z; o[3] = (bf16)v.w;
    ((bf16x4*)xb)[idx] = o;
    return;
  }

  const float* W; bf16* WT; int N, tb;
  if (blk < 4096 + 3072) { tb = blk - 4096; W = Wqkv;  WT = wqkvT;  N = 3 * C_; }
  else                   { tb = blk - 7168; W = Wproj; WT = wprojT; N = C_;     }
  const int xt = N / 32;
  const int n0 = (tb % xt) * 32, k0 = (tb / xt) * 32;
  const int tx = tid & 31, ty = tid >> 5;

  #pragma unroll
  for (int i = 0; i < 32; i += 8)
    t[ty + i][tx] = W[(size_t)(k0 + ty + i) * N + (n0 + tx)];
  __syncthreads();
  #pragma unroll
  for (int i = 0; i < 32; i += 8)
    WT[(size_t)(n0 + ty + i) * C_ + (k0 + tx)] = (bf16)t[tx][ty + i];
}

// ---------------- double-buffered MFMA GEMM (R9/R13 winning structure) ----------------
// + T1 XCD-chunked bijective blockIdx swizzle (nwg % 8 == 0 for all launches):
//   each XCD gets a contiguous run of linear block ids -> few B-panels, L2-resident.

template <int TM, int TN, int WM, int WN, int MINW, int MODE>
__global__ __launch_bounds__(WM * WN * 64, MINW)
void gemm_db_k(const bf16* __restrict__ A, const bf16* __restrict__ Bt,
               const float* __restrict__ bias,
               void* __restrict__ out0, void* __restrict__ out1,
               int M, int N, int K) {
  constexpr int NW    = WM * WN;
  constexpr int WROWS = TM / WM;
  constexpr int WCOLS = TN / WN;
  constexpr int FM    = WROWS / 16;
  constexpr int FN    = WCOLS / 16;
  constexpr int NCH   = (TM + TN) / 8;
  constexpr int CPW   = NCH / NW;

  // XCD-chunked swizzle (bijective when nwg % 8 == 0; both launches use 512)
  int bid = blockIdx.y * gridDim.x + blockIdx.x;
  const int nwg = gridDim.x * gridDim.y;
  bid = (bid & 7) * (nwg >> 3) + (bid >> 3);
  const int bm = (bid % gridDim.x) * TM;
  const int bn = (bid / gridDim.x) * TN;

  const int tid  = threadIdx.x;
  const int wid  = tid >> 6;
  const int lane = tid & 63;
  const int wr = wid / WN;
  const int wc = wid % WN;
  const int lr = lane & 15;
  const int g  = lane >> 4;

  __shared__ bf16 As[2][TM * 64];
  __shared__ bf16 Bs[2][TN * 64];

  f32x4 acc[FM][FN] = {};

  const int sr = lane >> 3;
  const int sc = ((lane & 7) ^ sr) << 3;

  #define STG(p_, u_)                                                        \
    do {                                                                     \
      _Pragma("unroll")                                                      \
      for (int i = 0; i < CPW; ++i) {                                        \
        const int c = wid * CPW + i;                                         \
        if (c < TM / 8) {                                                    \
          GLOAD16(A + (size_t)(bm + c * 8 + sr) * K + (u_) * 64 + sc,        \
                  &As[p_][c * 8 * 64]);                                      \
        } else {                                                             \
          GLOAD16(Bt + (size_t)(bn + (c - TM / 8) * 8 + sr) * K + (u_) * 64 + sc, \
                  &Bs[p_][(c - TM / 8) * 8 * 64]);                           \
        }                                                                    \
      }                                                                      \
    } while (0)

  const int NT = K >> 6;
  const int kc0 = ((0 + g) ^ (lr & 7)) << 3;
  const int kc1 = ((4 + g) ^ (lr & 7)) << 3;

  STG(0, 0);
  asm volatile("s_waitcnt vmcnt(0)" ::: "memory");
  __builtin_amdgcn_s_barrier();
  asm volatile("" ::: "memory");

  for (int u = 0; u < NT; ++u) {
    const int p = u & 1;
    if (u + 1 < NT) {
      STG(p ^ 1, u + 1);
      asm volatile("s_waitcnt vmcnt(%0)" :: "i"(CPW) : "memory");
    } else {
      asm volatile("s_waitcnt vmcnt(0)" ::: "memory");
    }
    bar();

    const bf16* Ar = &As[p][(wr * WROWS + lr) * 64];
    const bf16* Br = &Bs[p][(wc * WCOLS + lr) * 64];
    #pragma unroll
    for (int s = 0; s < 2; ++s) {
      const int kc = s ? kc1 : kc0;
      bf16x8 av[FM], bvv[FN];
      #pragma unroll
      for (int m = 0; m < FM; ++m)
        av[m] = *(const bf16x8*)(Ar + m * 16 * 64 + kc);
      #pragma unroll
      for (int n = 0; n < FN; ++n)
        bvv[n] = *(const bf16x8*)(Br + n * 16 * 64 + kc);
      __builtin_amdgcn_s_setprio(1);
      #pragma unroll
      for (int m = 0; m < FM; ++m)
        #pragma unroll
        for (int n = 0; n < FN; ++n)
          acc[m][n] = __builtin_amdgcn_mfma_f32_16x16x32_bf16(av[m], bvv[n], acc[m][n], 0, 0, 0);
      __builtin_amdgcn_s_setprio(0);
    }
    bar();
  }
  #undef STG

  const int orow = g * 4;
  #pragma unroll
  for (int n = 0; n < FN; ++n) {
    const int nbase = bn + wc * WCOLS + n * 16;
    const int gn = nbase + lr;
    const float bv_ = bias[gn];
    #pragma unroll
    for (int m = 0; m < FM; ++m) {
      const int gm0 = bm + wr * WROWS + m * 16 + orow;
      if (MODE == 0) {
        #pragma unroll
        for (int r = 0; r < 4; ++r)
          ((float*)out0)[(size_t)(gm0 + r) * N + gn] = acc[m][n][r] + bv_;
      } else {
        if (nbase < 2 * C_) {
          #pragma unroll
          for (int r = 0; r < 4; ++r)
            ((bf16*)out0)[(size_t)(gm0 + r) * (2 * C_) + gn] = (bf16)(acc[m][n][r] + bv_);
        } else {
          const int vcol = gn - 2 * C_;
          const int h = vcol >> 6, d = vcol & 63;
          const int b = gm0 >> 11, tok = gm0 & (T_ - 1);
          bf16x4 o;
          #pragma unroll
          for (int r = 0; r < 4; ++r) o[r] = (bf16)(acc[m][n][r] + bv_);
          *(bf16x4*)&((bf16*)out1)[(((size_t)b * H_ + h) * HD_ + d) * T_ + tok] = o;
        }
      }
    }
  }
}

// ---------------- windowed flash attention v2 (R13 winning version) ----------------

__global__ __launch_bounds__(512) void attn_mfma2_k(const bf16* __restrict__ qk,
                                                    const bf16* __restrict__ vt,
                                                    bf16* __restrict__ y) {
  const int q0 = blockIdx.x * 128;
  const int h  = blockIdx.y;
  const int b  = blockIdx.z;
  const int tid  = threadIdx.x;
  const int wid  = tid >> 6;
  const int lane = tid & 63;
  const int lr = lane & 15;
  const int g  = lane >> 4;

  __shared__ bf16 Ks[2][64 * 64];
  __shared__ bf16 Vs[2][64 * 64];
  __shared__ bf16 Ps[8][16][72];

  const int qrow = q0 + wid * 16 + lr;
  const bf16* qptr = qk + ((size_t)(b * T_ + qrow)) * (2 * C_) + h * HD_;
  bf16x8 qf0 = *(const bf16x8*)(qptr + g * 8);
  bf16x8 qf1 = *(const bf16x8*)(qptr + 32 + g * 8);

  float m = -1e30f, l = 0.f;
  f32x4 yacc[4] = {};

  const int bx = blockIdx.x;
  const int kt_lo = (bx * 2 >= 4) ? bx * 2 - 4 : 0;
  const int kt_hi = bx * 2 + 1;

  const int sr = lane >> 3;
  const int sc = ((lane & 7) ^ sr) << 3;
  const int kc0 = ((0 + g) ^ (lr & 7)) << 3;
  const int kc1 = ((4 + g) ^ (lr & 7)) << 3;

  #define STAGEKV(p_, kt_)                                                     \
    do {                                                                       \
      _Pragma("unroll")                                                        \
      for (int i = 0; i < 2; ++i) {                                            \
        const int c = wid * 2 + i;                                             \
        if (c < 8)                                                             \
          GLOAD16(qk + ((size_t)(b * T_) + (kt_) * 64 + c * 8 + sr) * (2 * C_) \
                       + C_ + h * HD_ + sc,                                    \
                  &Ks[p_][c * 8 * 64]);                                        \
        else                                                                   \
          GLOAD16(vt + (((size_t)b * H_ + h) * HD_ + (c - 8) * 8 + sr) * T_    \
                       + (kt_) * 64 + sc,                                      \
                  &Vs[p_][(c - 8) * 8 * 64]);                                  \
      }                                                                        \
    } while (0)

  STAGEKV(0, kt_lo);
  asm volatile("s_waitcnt vmcnt(0)" ::: "memory");
  bar();

  for (int kt = kt_lo; kt <= kt_hi; ++kt) {
    const int idx = kt - kt_lo;
    const int p   = idx & 1;
    if (kt + 1 <= kt_hi) {
      STAGEKV(p ^ 1, kt + 1);
      asm volatile("s_waitcnt vmcnt(2)" ::: "memory");
    } else {
      asm volatile("s_waitcnt vmcnt(0)" ::: "memory");
    }
    bar();

    const int wq = q0 + wid * 16;
    if (kt * 64 <= wq + 15 && kt * 64 + 63 >= wq - WIN_) {
      f32x4 sacc[4] = {};
      __builtin_amdgcn_s_setprio(1);
      #pragma unroll
      for (int t = 0; t < 4; ++t) {
        sacc[t] = __builtin_amdgcn_mfma_f32_16x16x32_bf16(
            *(const bf16x8*)&Ks[p][(t * 16 + lr) * 64 + kc0], qf0, sacc[t], 0, 0, 0);
        sacc[t] = __builtin_amdgcn_mfma_f32_16x16x32_bf16(
            *(const bf16x8*)&Ks[p][(t * 16 + lr) * 64 + kc1], qf1, sacc[t], 0, 0, 0);
      }
      __builtin_amdgcn_s_setprio(0);

      float pv[4][4];
      float rmax = -1e30f;
      #pragma unroll
      for (int t = 0; t < 4; ++t)
        #pragma unroll
        for (int r = 0; r < 4; ++r) {
          const int key = kt * 64 + t * 16 + g * 4 + r;
          const bool valid = (key <= qrow) && (qrow - key <= WIN_);
          const float sv = valid ? sacc[t][r] * 0.125f : -__builtin_inff();
          pv[t][r] = sv;
          rmax = fmaxf(rmax, sv);
        }
      rmax = fmaxf(rmax, __shfl_xor(rmax, 16));
      rmax = fmaxf(rmax, __shfl_xor(rmax, 32));

      const float mnew = fmaxf(m, rmax);
      const float alpha = __expf(m - mnew);
      m = mnew;
      float lsum = 0.f;
      #pragma unroll
      for (int t = 0; t < 4; ++t)
        #pragma unroll
        for (int r = 0; r < 4; ++r) {
          const float e = __expf(pv[t][r] - mnew);
          pv[t][r] = e;
          lsum += e;
        }
      lsum += __shfl_xor(lsum, 16);
      lsum += __shfl_xor(lsum, 32);
      l = l * alpha + lsum;

      #pragma unroll
      for (int t = 0; t < 4; ++t) {
        bf16x4 pk;
        #pragma unroll
        for (int r = 0; r < 4; ++r) pk[r] = (bf16)pv[t][r];
        *(bf16x4*)&Ps[wid][lr][t * 16 + g * 4] = pk;
      }

      float al[4];
      #pragma unroll
      for (int r = 0; r < 4; ++r) al[r] = __shfl(alpha, g * 4 + r);
      #pragma unroll
      for (int t = 0; t < 4; ++t)
        #pragma unroll
        for (int r = 0; r < 4; ++r) yacc[t][r] *= al[r];

      bf16x8 pf0 = *(const bf16x8*)&Ps[wid][lr][g * 8];
      bf16x8 pf1 = *(const bf16x8*)&Ps[wid][lr][32 + g * 8];
      __builtin_amdgcn_s_setprio(1);
      #pragma unroll
      for (int t = 0; t < 4; ++t) {
        yacc[t] = __builtin_amdgcn_mfma_f32_16x16x32_bf16(
            pf0, *(const bf16x8*)&Vs[p][(t * 16 + lr) * 64 + kc0], yacc[t], 0, 0, 0);
        yacc[t] = __builtin_amdgcn_mfma_f32_16x16x32_bf16(
            pf1, *(const bf16x8*)&Vs[p][(t * 16 + lr) * 64 + kc1], yacc[t], 0, 0, 0);
      }
      __builtin_amdgcn_s_setprio(0);
    }
    bar();
  }
  #undef STAGEKV

  float li[4];
  #pragma unroll
  for (int r = 0; r < 4; ++r) li[r] = 1.f / __shfl(l, g * 4 + r);
  #pragma unroll
  for (int t = 0; t < 4; ++t)
    #pragma unroll
    for (int r = 0; r < 4; ++r) {
      const int tok = q0 + wid * 16 + g * 4 + r;
      y[((size_t)(b * T_ + tok)) * C_ + h * HD_ + t * 16 + lr] = (bf16)(yacc[t][r] * li[r]);
    }
}

// ---------------- launch ----------------

extern "C" void kernel_launch(void* const* d_in, const int* in_sizes, int n_in,
                              void* d_out, int out_size, void* d_ws, size_t ws_size,
                              hipStream_t stream) {
  const float* x     = (const float*)d_in[0];
  const float* Wqkv  = (const float*)d_in[1];
  const float* bqkv  = (const float*)d_in[2];
  const float* Wproj = (const float*)d_in[3];
  const float* bproj = (const float*)d_in[4];
  float* out = (float*)d_out;

  const size_t SZ_QK  = (size_t)B_ * T_ * 2 * C_ * sizeof(bf16);
  const size_t SZ_VT  = (size_t)B_ * H_ * HD_ * T_ * sizeof(bf16);
  const size_t SZ_XB  = (size_t)B_ * T_ * C_ * sizeof(bf16);
  const size_t SZ_WQT = (size_t)3 * C_ * C_ * sizeof(bf16);
  const size_t SZ_WPT = (size_t)C_ * C_ * sizeof(bf16);
  const size_t NEED   = SZ_QK + SZ_VT + SZ_XB + SZ_WQT + SZ_WPT + SZ_XB;
  if (ws_size < NEED) return;

  char* ws = (char*)d_ws;
  bf16* qkb    = (bf16*)(ws);
  bf16* vtb    = (bf16*)(ws + SZ_QK);
  bf16* xb     = (bf16*)(ws + SZ_QK + SZ_VT);
  bf16* wqkvT  = (bf16*)(ws + SZ_QK + SZ_VT + SZ_XB);
  bf16* wprojT = (bf16*)(ws + SZ_QK + SZ_VT + SZ_XB + SZ_WQT);
  bf16* yb     = (bf16*)(ws + SZ_QK + SZ_VT + SZ_XB + SZ_WQT + SZ_WPT);

  // merged prologue: 4096 cvt blocks + 3072 + 1024 transpose blocks
  prologue_k<<<8192, 256, 0, stream>>>(x, xb, Wqkv, wqkvT, Wproj, wprojT);

  // qkv: 128x192 tiles, 8 waves, LDS 80KB -> 2 blocks/CU; grid 32x16=512
  gemm_db_k<128, 192, 2, 4, 4, 2><<<dim3((B_ * T_) / 128, (3 * C_) / 192), 512, 0, stream>>>(
      xb, wqkvT, bqkv, qkb, vtb, B_ * T_, 3 * C_, C_);

  // attn v2: 128 q rows/block, 8 waves; grid 16x16x2 = 512 = 2 blocks/CU
  attn_mfma2_k<<<dim3(T_ / 128, H_, B_), 512, 0, stream>>>(qkb, vtb, yb);

  // proj: 64x128 tiles, 4 waves, LDS 48KB; grid 64x8=512 -> 2 blocks/CU
  gemm_db_k<64, 128, 2, 2, 2, 0><<<dim3((B_ * T_) / 64, C_ / 128), 256, 0, stream>>>(
      yb, wprojT, bproj, out, nullptr, B_ * T_, C_, C_);
}

// Round 18
// 80.228 us; speedup vs baseline: 3.4434x; 1.0224x over previous
//
#include <hip/hip_runtime.h>
#include <hip/hip_bf16.h>
#include <math.h>

typedef __bf16 bf16;
typedef __attribute__((ext_vector_type(8))) __bf16 bf16x8;
typedef __attribute__((ext_vector_type(4))) __bf16 bf16x4;
typedef __attribute__((ext_vector_type(4))) float f32x4;

#define B_  2
#define T_  2048
#define C_  1024
#define H_  16
#define HD_ 64
#define WIN_ 256

// async global->LDS, 16B per lane, dest = wave-uniform base + lane*16
#define GLOAD16(g, l)                                                        \
  __builtin_amdgcn_global_load_lds(                                          \
      (const __attribute__((address_space(1))) void*)(g),                    \
      (__attribute__((address_space(3))) void*)(l), 16, 0, 0)

__device__ inline void bar() {
  asm volatile("" ::: "memory");
  __builtin_amdgcn_s_barrier();
  asm volatile("" ::: "memory");
}

// ---------------- merged prologue: cvt x + transpose both weights ----------------

__global__ __launch_bounds__(256) void prologue_k(const float* __restrict__ x,
                                                  bf16* __restrict__ xb,
                                                  const float* __restrict__ Wqkv,
                                                  bf16* __restrict__ wqkvT,
                                                  const float* __restrict__ Wproj,
                                                  bf16* __restrict__ wprojT) {
  __shared__ float t[32][33];
  const int blk = blockIdx.x;
  const int tid = threadIdx.x;

  if (blk < 4096) {
    const int idx = blk * 256 + tid;
    const float4 v = ((const float4*)x)[idx];
    bf16x4 o;
    o[0] = (bf16)v.x; o[1] = (bf16)v.y; o[2] = (bf16)v.z; o[3] = (bf16)v.w;
    ((bf16x4*)xb)[idx] = o;
    return;
  }

  const float* W; bf16* WT; int N, tb;
  if (blk < 4096 + 3072) { tb = blk - 4096; W = Wqkv;  WT = wqkvT;  N = 3 * C_; }
  else                   { tb = blk - 7168; W = Wproj; WT = wprojT; N = C_;     }
  const int xt = N / 32;
  const int n0 = (tb % xt) * 32, k0 = (tb / xt) * 32;
  const int tx = tid & 31, ty = tid >> 5;

  #pragma unroll
  for (int i = 0; i < 32; i += 8)
    t[ty + i][tx] = W[(size_t)(k0 + ty + i) * N + (n0 + tx)];
  __syncthreads();
  #pragma unroll
  for (int i = 0; i < 32; i += 8)
    WT[(size_t)(n0 + ty + i) * C_ + (k0 + tx)] = (bf16)t[tx][ty + i];
}

// ---------------- double-buffered MFMA GEMM, sized for 2 blocks/CU ----------------
// (R9/R13 winning structure; no XCD swizzle — regressed on this L3-resident problem)

template <int TM, int TN, int WM, int WN, int MINW, int MODE>
__global__ __launch_bounds__(WM * WN * 64, MINW)
void gemm_db_k(const bf16* __restrict__ A, const bf16* __restrict__ Bt,
               const float* __restrict__ bias,
               void* __restrict__ out0, void* __restrict__ out1,
               int M, int N, int K) {
  constexpr int NW    = WM * WN;
  constexpr int WROWS = TM / WM;
  constexpr int WCOLS = TN / WN;
  constexpr int FM    = WROWS / 16;
  constexpr int FN    = WCOLS / 16;
  constexpr int NCH   = (TM + TN) / 8;
  constexpr int CPW   = NCH / NW;

  const int bm = blockIdx.x * TM;
  const int bn = blockIdx.y * TN;
  const int tid  = threadIdx.x;
  const int wid  = tid >> 6;
  const int lane = tid & 63;
  const int wr = wid / WN;
  const int wc = wid % WN;
  const int lr = lane & 15;
  const int g  = lane >> 4;

  __shared__ bf16 As[2][TM * 64];
  __shared__ bf16 Bs[2][TN * 64];

  f32x4 acc[FM][FN] = {};

  const int sr = lane >> 3;
  const int sc = ((lane & 7) ^ sr) << 3;

  #define STG(p_, u_)                                                        \
    do {                                                                     \
      _Pragma("unroll")                                                      \
      for (int i = 0; i < CPW; ++i) {                                        \
        const int c = wid * CPW + i;                                         \
        if (c < TM / 8) {                                                    \
          GLOAD16(A + (size_t)(bm + c * 8 + sr) * K + (u_) * 64 + sc,        \
                  &As[p_][c * 8 * 64]);                                      \
        } else {                                                             \
          GLOAD16(Bt + (size_t)(bn + (c - TM / 8) * 8 + sr) * K + (u_) * 64 + sc, \
                  &Bs[p_][(c - TM / 8) * 8 * 64]);                           \
        }                                                                    \
      }                                                                      \
    } while (0)

  const int NT = K >> 6;
  const int kc0 = ((0 + g) ^ (lr & 7)) << 3;
  const int kc1 = ((4 + g) ^ (lr & 7)) << 3;

  STG(0, 0);
  asm volatile("s_waitcnt vmcnt(0)" ::: "memory");
  __builtin_amdgcn_s_barrier();
  asm volatile("" ::: "memory");

  for (int u = 0; u < NT; ++u) {
    const int p = u & 1;
    if (u + 1 < NT) {
      STG(p ^ 1, u + 1);
      asm volatile("s_waitcnt vmcnt(%0)" :: "i"(CPW) : "memory");
    } else {
      asm volatile("s_waitcnt vmcnt(0)" ::: "memory");
    }
    bar();

    const bf16* Ar = &As[p][(wr * WROWS + lr) * 64];
    const bf16* Br = &Bs[p][(wc * WCOLS + lr) * 64];
    #pragma unroll
    for (int s = 0; s < 2; ++s) {
      const int kc = s ? kc1 : kc0;
      bf16x8 av[FM], bvv[FN];
      #pragma unroll
      for (int m = 0; m < FM; ++m)
        av[m] = *(const bf16x8*)(Ar + m * 16 * 64 + kc);
      #pragma unroll
      for (int n = 0; n < FN; ++n)
        bvv[n] = *(const bf16x8*)(Br + n * 16 * 64 + kc);
      __builtin_amdgcn_s_setprio(1);
      #pragma unroll
      for (int m = 0; m < FM; ++m)
        #pragma unroll
        for (int n = 0; n < FN; ++n)
          acc[m][n] = __builtin_amdgcn_mfma_f32_16x16x32_bf16(av[m], bvv[n], acc[m][n], 0, 0, 0);
      __builtin_amdgcn_s_setprio(0);
    }
    bar();
  }
  #undef STG

  const int orow = g * 4;
  #pragma unroll
  for (int n = 0; n < FN; ++n) {
    const int nbase = bn + wc * WCOLS + n * 16;
    const int gn = nbase + lr;
    const float bv_ = bias[gn];
    #pragma unroll
    for (int m = 0; m < FM; ++m) {
      const int gm0 = bm + wr * WROWS + m * 16 + orow;
      if (MODE == 0) {
        #pragma unroll
        for (int r = 0; r < 4; ++r)
          ((float*)out0)[(size_t)(gm0 + r) * N + gn] = acc[m][n][r] + bv_;
      } else {
        if (nbase < 2 * C_) {
          #pragma unroll
          for (int r = 0; r < 4; ++r)
            ((bf16*)out0)[(size_t)(gm0 + r) * (2 * C_) + gn] = (bf16)(acc[m][n][r] + bv_);
        } else {
          const int vcol = gn - 2 * C_;
          const int h = vcol >> 6, d = vcol & 63;
          const int b = gm0 >> 11, tok = gm0 & (T_ - 1);
          bf16x4 o;
          #pragma unroll
          for (int r = 0; r < 4; ++r) o[r] = (bf16)(acc[m][n][r] + bv_);
          *(bf16x4*)&((bf16*)out1)[(((size_t)b * H_ + h) * HD_ + d) * T_ + tok] = o;
        }
      }
    }
  }
}

// ---------------- windowed flash attention v2 (R13 winning version) ----------------

__global__ __launch_bounds__(512) void attn_mfma2_k(const bf16* __restrict__ qk,
                                                    const bf16* __restrict__ vt,
                                                    bf16* __restrict__ y) {
  const int q0 = blockIdx.x * 128;
  const int h  = blockIdx.y;
  const int b  = blockIdx.z;
  const int tid  = threadIdx.x;
  const int wid  = tid >> 6;
  const int lane = tid & 63;
  const int lr = lane & 15;
  const int g  = lane >> 4;

  __shared__ bf16 Ks[2][64 * 64];
  __shared__ bf16 Vs[2][64 * 64];
  __shared__ bf16 Ps[8][16][72];

  const int qrow = q0 + wid * 16 + lr;
  const bf16* qptr = qk + ((size_t)(b * T_ + qrow)) * (2 * C_) + h * HD_;
  bf16x8 qf0 = *(const bf16x8*)(qptr + g * 8);
  bf16x8 qf1 = *(const bf16x8*)(qptr + 32 + g * 8);

  float m = -1e30f, l = 0.f;
  f32x4 yacc[4] = {};

  const int bx = blockIdx.x;
  const int kt_lo = (bx * 2 >= 4) ? bx * 2 - 4 : 0;
  const int kt_hi = bx * 2 + 1;

  const int sr = lane >> 3;
  const int sc = ((lane & 7) ^ sr) << 3;
  const int kc0 = ((0 + g) ^ (lr & 7)) << 3;
  const int kc1 = ((4 + g) ^ (lr & 7)) << 3;

  #define STAGEKV(p_, kt_)                                                     \
    do {                                                                       \
      _Pragma("unroll")                                                        \
      for (int i = 0; i < 2; ++i) {                                            \
        const int c = wid * 2 + i;                                             \
        if (c < 8)                                                             \
          GLOAD16(qk + ((size_t)(b * T_) + (kt_) * 64 + c * 8 + sr) * (2 * C_) \
                       + C_ + h * HD_ + sc,                                    \
                  &Ks[p_][c * 8 * 64]);                                        \
        else                                                                   \
          GLOAD16(vt + (((size_t)b * H_ + h) * HD_ + (c - 8) * 8 + sr) * T_    \
                       + (kt_) * 64 + sc,                                      \
                  &Vs[p_][(c - 8) * 8 * 64]);                                  \
      }                                                                        \
    } while (0)

  STAGEKV(0, kt_lo);
  asm volatile("s_waitcnt vmcnt(0)" ::: "memory");
  bar();

  for (int kt = kt_lo; kt <= kt_hi; ++kt) {
    const int idx = kt - kt_lo;
    const int p   = idx & 1;
    if (kt + 1 <= kt_hi) {
      STAGEKV(p ^ 1, kt + 1);
      asm volatile("s_waitcnt vmcnt(2)" ::: "memory");
    } else {
      asm volatile("s_waitcnt vmcnt(0)" ::: "memory");
    }
    bar();

    const int wq = q0 + wid * 16;
    if (kt * 64 <= wq + 15 && kt * 64 + 63 >= wq - WIN_) {
      f32x4 sacc[4] = {};
      __builtin_amdgcn_s_setprio(1);
      #pragma unroll
      for (int t = 0; t < 4; ++t) {
        sacc[t] = __builtin_amdgcn_mfma_f32_16x16x32_bf16(
            *(const bf16x8*)&Ks[p][(t * 16 + lr) * 64 + kc0], qf0, sacc[t], 0, 0, 0);
        sacc[t] = __builtin_amdgcn_mfma_f32_16x16x32_bf16(
            *(const bf16x8*)&Ks[p][(t * 16 + lr) * 64 + kc1], qf1, sacc[t], 0, 0, 0);
      }
      __builtin_amdgcn_s_setprio(0);

      float pv[4][4];
      float rmax = -1e30f;
      #pragma unroll
      for (int t = 0; t < 4; ++t)
        #pragma unroll
        for (int r = 0; r < 4; ++r) {
          const int key = kt * 64 + t * 16 + g * 4 + r;
          const bool valid = (key <= qrow) && (qrow - key <= WIN_);
          const float sv = valid ? sacc[t][r] * 0.125f : -__builtin_inff();
          pv[t][r] = sv;
          rmax = fmaxf(rmax, sv);
        }
      rmax = fmaxf(rmax, __shfl_xor(rmax, 16));
      rmax = fmaxf(rmax, __shfl_xor(rmax, 32));

      const float mnew = fmaxf(m, rmax);
      const float alpha = __expf(m - mnew);
      m = mnew;
      float lsum = 0.f;
      #pragma unroll
      for (int t = 0; t < 4; ++t)
        #pragma unroll
        for (int r = 0; r < 4; ++r) {
          const float e = __expf(pv[t][r] - mnew);
          pv[t][r] = e;
          lsum += e;
        }
      lsum += __shfl_xor(lsum, 16);
      lsum += __shfl_xor(lsum, 32);
      l = l * alpha + lsum;

      #pragma unroll
      for (int t = 0; t < 4; ++t) {
        bf16x4 pk;
        #pragma unroll
        for (int r = 0; r < 4; ++r) pk[r] = (bf16)pv[t][r];
        *(bf16x4*)&Ps[wid][lr][t * 16 + g * 4] = pk;
      }

      float al[4];
      #pragma unroll
      for (int r = 0; r < 4; ++r) al[r] = __shfl(alpha, g * 4 + r);
      #pragma unroll
      for (int t = 0; t < 4; ++t)
        #pragma unroll
        for (int r = 0; r < 4; ++r) yacc[t][r] *= al[r];

      bf16x8 pf0 = *(const bf16x8*)&Ps[wid][lr][g * 8];
      bf16x8 pf1 = *(const bf16x8*)&Ps[wid][lr][32 + g * 8];
      __builtin_amdgcn_s_setprio(1);
      #pragma unroll
      for (int t = 0; t < 4; ++t) {
        yacc[t] = __builtin_amdgcn_mfma_f32_16x16x32_bf16(
            pf0, *(const bf16x8*)&Vs[p][(t * 16 + lr) * 64 + kc0], yacc[t], 0, 0, 0);
        yacc[t] = __builtin_amdgcn_mfma_f32_16x16x32_bf16(
            pf1, *(const bf16x8*)&Vs[p][(t * 16 + lr) * 64 + kc1], yacc[t], 0, 0, 0);
      }
      __builtin_amdgcn_s_setprio(0);
    }
    bar();
  }
  #undef STAGEKV

  float li[4];
  #pragma unroll
  for (int r = 0; r < 4; ++r) li[r] = 1.f / __shfl(l, g * 4 + r);
  #pragma unroll
  for (int t = 0; t < 4; ++t)
    #pragma unroll
    for (int r = 0; r < 4; ++r) {
      const int tok = q0 + wid * 16 + g * 4 + r;
      y[((size_t)(b * T_ + tok)) * C_ + h * HD_ + t * 16 + lr] = (bf16)(yacc[t][r] * li[r]);
    }
}

// ---------------- launch ----------------

extern "C" void kernel_launch(void* const* d_in, const int* in_sizes, int n_in,
                              void* d_out, int out_size, void* d_ws, size_t ws_size,
                              hipStream_t stream) {
  const float* x     = (const float*)d_in[0];
  const float* Wqkv  = (const float*)d_in[1];
  const float* bqkv  = (const float*)d_in[2];
  const float* Wproj = (const float*)d_in[3];
  const float* bproj = (const float*)d_in[4];
  float* out = (float*)d_out;

  const size_t SZ_QK  = (size_t)B_ * T_ * 2 * C_ * sizeof(bf16);
  const size_t SZ_VT  = (size_t)B_ * H_ * HD_ * T_ * sizeof(bf16);
  const size_t SZ_XB  = (size_t)B_ * T_ * C_ * sizeof(bf16);
  const size_t SZ_WQT = (size_t)3 * C_ * C_ * sizeof(bf16);
  const size_t SZ_WPT = (size_t)C_ * C_ * sizeof(bf16);
  const size_t NEED   = SZ_QK + SZ_VT + SZ_XB + SZ_WQT + SZ_WPT + SZ_XB;
  if (ws_size < NEED) return;

  char* ws = (char*)d_ws;
  bf16* qkb    = (bf16*)(ws);
  bf16* vtb    = (bf16*)(ws + SZ_QK);
  bf16* xb     = (bf16*)(ws + SZ_QK + SZ_VT);
  bf16* wqkvT  = (bf16*)(ws + SZ_QK + SZ_VT + SZ_XB);
  bf16* wprojT = (bf16*)(ws + SZ_QK + SZ_VT + SZ_XB + SZ_WQT);
  bf16* yb     = (bf16*)(ws + SZ_QK + SZ_VT + SZ_XB + SZ_WQT + SZ_WPT);

  // merged prologue: 4096 cvt blocks + 3072 + 1024 transpose blocks
  prologue_k<<<8192, 256, 0, stream>>>(x, xb, Wqkv, wqkvT, Wproj, wprojT);

  // qkv: 128x192 tiles, 8 waves, LDS 80KB -> 2 blocks/CU; grid 32x16=512
  gemm_db_k<128, 192, 2, 4, 4, 2><<<dim3((B_ * T_) / 128, (3 * C_) / 192), 512, 0, stream>>>(
      xb, wqkvT, bqkv, qkb, vtb, B_ * T_, 3 * C_, C_);

  // attn v2: 128 q rows/block, 8 waves; grid 16x16x2 = 512 = 2 blocks/CU
  attn_mfma2_k<<<dim3(T_ / 128, H_, B_), 512, 0, stream>>>(qkb, vtb, yb);

  // proj: 64x128 tiles, 4 waves, LDS 48KB; grid 64x8=512 -> 2 blocks/CU
  gemm_db_k<64, 128, 2, 2, 2, 0><<<dim3((B_ * T_) / 64, C_ / 128), 256, 0, stream>>>(
      yb, wprojT, bproj, out, nullptr, B_ * T_, C_, C_);
}